// Round 11
// baseline (272.112 us; speedup 1.0000x reference)
//
#include <hip/hip_runtime.h>
#include <stdint.h>

#define N_Q    4096
#define D_K    512
#define D_OUT  16384
#define NCLUST 256

// GEMM: 128x128 tile, BK=32, 4 waves (2x2), 64x64 per wave.
// Round-11 lever: ring-2 LDS (32 KB) -> 5 WG/CU (20 waves) vs round-8's
// ring-3/3WG. m97-style loop (stage t+1 during t, drain at tile top);
// per-tile drain covered by TLP across 5 co-resident WGs, and 5 independent
// epilogue store-drains interleave with K-loops (C-write ~43us device floor).
// T2 swizzle, setprio, XCD panel mapping, LDS-transposed full-line nt epilogue.
#define BM 128
#define BN 128
#define BK 32
#define NT (D_K / BK)   // 16 K-tiles
#define SCP 132         // sC row stride in floats (non-pow2: conflict-free)

typedef __attribute__((ext_vector_type(4))) float f32x4;
typedef __attribute__((ext_vector_type(8))) short bf16x8;

// round-to-nearest-even f32 -> bf16
__device__ __forceinline__ uint32_t f2bf(float f) {
  uint32_t u = __float_as_uint(f);
  u += 0x7FFFu + ((u >> 16) & 1u);
  return u >> 16;
}

#define GLOAD_LDS16(g, l)                                         \
  __builtin_amdgcn_global_load_lds(                               \
      (const __attribute__((address_space(1))) void*)(g),         \
      (__attribute__((address_space(3))) void*)(l), 16, 0, 0)

// vmcnt wait fused with barrier (K-loop top); memory clobber pins mem ops
#define WAIT_BAR(N) asm volatile("s_waitcnt vmcnt(" #N ")\n\ts_barrier" ::: "memory")
// lgkm-only barrier (epilogue): never drains vmcnt -> nt stores stay in flight
#define LBAR() asm volatile("s_waitcnt lgkmcnt(0)\n\ts_barrier" ::: "memory")

// merged: W f32->bf16 convert (blocks 0..4095) + centroid transpose (4096..4223)
__global__ __launch_bounds__(256) void prep_kernel(const float* __restrict__ weight,
                                                   ushort* __restrict__ W_bf,
                                                   const float* __restrict__ cent,
                                                   float4* __restrict__ centT4,
                                                   float* __restrict__ cmask) {
  int b = blockIdx.x;
  if (b < (D_OUT * D_K / 8) / 256) {
    int i = b * 256 + threadIdx.x;
    const float4* s = reinterpret_cast<const float4*>(weight) + (size_t)i * 2;
    float4 v0 = s[0], v1 = s[1];
    uint4 o;
    o.x = f2bf(v0.x) | (f2bf(v0.y) << 16);
    o.y = f2bf(v0.z) | (f2bf(v0.w) << 16);
    o.z = f2bf(v1.x) | (f2bf(v1.y) << 16);
    o.w = f2bf(v1.z) | (f2bf(v1.w) << 16);
    reinterpret_cast<uint4*>(W_bf)[i] = o;
  } else {
    int bb = b - (D_OUT * D_K / 8) / 256;
    if (bb == 0) cmask[threadIdx.x] = 0.0f;
    int idx = bb * 256 + threadIdx.x;
    int k4 = idx & 127, c = idx >> 7;
    float4 v = *reinterpret_cast<const float4*>(&cent[(size_t)c * D_K + k4 * 4]);
    centT4[(size_t)k4 * NCLUST + c] = v;
  }
}

// 8 queries/block; thread t owns centroid t; fused A f32->bf16 convert.
// f32 routing math throughout (threshold booleans must not flip).
__global__ __launch_bounds__(256) void routing_kernel(const float* __restrict__ input,
                                                      const float4* __restrict__ centT4,
                                                      float* __restrict__ qmask,
                                                      float* __restrict__ cmask,
                                                      ushort* __restrict__ A_bf) {
  __shared__ float lgs[8][NCLUST];
  int c = threadIdx.x;
  int q0 = blockIdx.x * 8;
  const float* __restrict__ inp = input + (size_t)q0 * D_K;

  {
    const float4* s4 = reinterpret_cast<const float4*>(inp) + c * 4;
    float4 x0 = s4[0], x1 = s4[1], x2 = s4[2], x3 = s4[3];
    uint4 o0, o1;
    o0.x = f2bf(x0.x) | (f2bf(x0.y) << 16);
    o0.y = f2bf(x0.z) | (f2bf(x0.w) << 16);
    o0.z = f2bf(x1.x) | (f2bf(x1.y) << 16);
    o0.w = f2bf(x1.z) | (f2bf(x1.w) << 16);
    o1.x = f2bf(x2.x) | (f2bf(x2.y) << 16);
    o1.y = f2bf(x2.z) | (f2bf(x2.w) << 16);
    o1.z = f2bf(x3.x) | (f2bf(x3.y) << 16);
    o1.w = f2bf(x3.z) | (f2bf(x3.w) << 16);
    uint4* dst = reinterpret_cast<uint4*>(A_bf + (size_t)q0 * D_K);
    dst[c * 2] = o0;
    dst[c * 2 + 1] = o1;
  }

  float acc[8] = {0, 0, 0, 0, 0, 0, 0, 0};
  for (int k4 = 0; k4 < D_K / 4; ++k4) {
    float4 v = centT4[(size_t)k4 * NCLUST + c];
#pragma unroll
    for (int q = 0; q < 8; ++q) {
      float4 r = *reinterpret_cast<const float4*>(&inp[q * D_K + k4 * 4]);  // uniform addr
      acc[q] += v.x * r.x + v.y * r.y + v.z * r.z + v.w * r.w;
    }
  }
#pragma unroll
  for (int q = 0; q < 8; ++q) lgs[q][c] = acc[q] * 10.0f;  // /TEMPERATURE
  __syncthreads();

  int wave = c >> 6, lane = c & 63;
#pragma unroll
  for (int qq = 0; qq < 2; ++qq) {
    int q = wave * 2 + qq;
    float4 lv = *reinterpret_cast<const float4*>(&lgs[q][lane * 4]);
    float m = fmaxf(fmaxf(lv.x, lv.y), fmaxf(lv.z, lv.w));
#pragma unroll
    for (int off = 32; off > 0; off >>= 1) m = fmaxf(m, __shfl_xor(m, off));
    float e0 = expf(lv.x - m), e1 = expf(lv.y - m), e2 = expf(lv.z - m), e3 = expf(lv.w - m);
    float s = e0 + e1 + e2 + e3;
#pragma unroll
    for (int off = 32; off > 0; off >>= 1) s += __shfl_xor(s, off);
    float thr = 0.01f * s;
    bool a0 = e0 > thr, a1 = e1 > thr, a2 = e2 > thr, a3 = e3 > thr;
    if (a0) cmask[lane * 4 + 0] = 1.0f;  // benign races: all writers store 1.0
    if (a1) cmask[lane * 4 + 1] = 1.0f;
    if (a2) cmask[lane * 4 + 2] = 1.0f;
    if (a3) cmask[lane * 4 + 3] = 1.0f;
    unsigned long long any = __ballot(a0 | a1 | a2 | a3);
    if (lane == 0) qmask[q0 + q] = any ? 1.0f : 0.0f;
  }
}

__global__ __launch_bounds__(256, 5) void gemm_masked_kernel(
    const ushort* __restrict__ A, const ushort* __restrict__ W,
    const float* __restrict__ bias, const int* __restrict__ assign,
    const float* __restrict__ qmask, const float* __restrict__ cmask,
    float* __restrict__ C) {
  // LDS 32 KB: 2 slots of 16 KB = {A tile 8K | B tile 8K}. 5 WG/CU.
  // Epilogue reuses the front 16.9 KB as sC[32][SCP] (block-terminal).
  __shared__ __align__(16) char smem[32768];

  int tid = threadIdx.x;
  int wave = tid >> 6, lane = tid & 63;

  // XCD mapping: xcd = bid&7 owns ntiles [16x,16x+16); ntile fast within XCD
  // (2 MB W-set L2-resident); 4096 % 8 == 0 -> bijective.
  int bid = blockIdx.x;
  int idx = bid >> 3;                         // 0..511
  int ntile = (bid & 7) * 16 + (idx & 15);    // 0..127
  int mtile = idx >> 4;                       // 0..31
  int m0 = mtile * BM, n0 = ntile * BN;

  int wr = wave >> 1, wc = wave & 1;  // 2x2 wave grid; per-wave C: 64x64

  // staging: LDS (row,kg) <- global (row, kg ^ ((row>>1)&3)); linear LDS dest,
  // pre-swizzled per-lane source (rule #21). ((64+r)>>1)&3 == ((r>>1)&3) ✓.
  int srow = tid >> 2, kg = tid & 3;
  int ks = (kg ^ ((srow >> 1) & 3)) * 8;
  const ushort* srcA0 = A + (size_t)(m0 + srow) * D_K + ks;       // rows 0..63
  const ushort* srcA1 = srcA0 + (size_t)64 * D_K;                 // rows 64..127
  const ushort* srcB0 = W + (size_t)(n0 + srow) * D_K + ks;
  const ushort* srcB1 = srcB0 + (size_t)64 * D_K;
  int wo = wave << 10;  // wave's 1 KB chunk within each 4 KB op region

#define STAGE(j) do {                                    \
    char* sl_ = smem + ((j) & 1) * 16384 + wo;           \
    GLOAD_LDS16(srcA0 + (j) * BK, sl_);                  \
    GLOAD_LDS16(srcA1 + (j) * BK, sl_ + 4096);           \
    GLOAD_LDS16(srcB0 + (j) * BK, sl_ + 8192);           \
    GLOAD_LDS16(srcB1 + (j) * BK, sl_ + 12288);          \
  } while (0)

  // fragment read indices (swizzled), ushort units within a slot
  int kg0 = lane >> 4, l15 = lane & 15, lr = lane >> 4;
  int aIdx[4], bIdx[4];
#pragma unroll
  for (int m = 0; m < 4; ++m) {
    int r = wr * 64 + m * 16 + l15;
    aIdx[m] = r * 32 + ((kg0 ^ ((r >> 1) & 3)) << 3);
  }
#pragma unroll
  for (int n = 0; n < 4; ++n) {
    int r = wc * 64 + n * 16 + l15;
    bIdx[n] = 4096 + r * 32 + ((kg0 ^ ((r >> 1) & 3)) << 3);  // B at +8 KB
  }

  f32x4 acc[4][4] = {};

  STAGE(0);

#pragma unroll
  for (int t = 0; t < NT; ++t) {
    // loop top: drain tile t's 4 loads (issued last iter; ~1 tile of flight
    // time; residual covered by 5-WG TLP). Barrier aligns waves & retires
    // slot (t+1)&1's reads from iter t-1 before STAGE(t+1) overwrites it.
    WAIT_BAR(0);

    const ushort* sl = (const ushort*)(smem + (t & 1) * 16384);
    bf16x8 af[4], bf[4];
#pragma unroll
    for (int n = 0; n < 4; ++n) bf[n] = *reinterpret_cast<const bf16x8*>(&sl[bIdx[n]]);
#pragma unroll
    for (int m = 0; m < 4; ++m) af[m] = *reinterpret_cast<const bf16x8*>(&sl[aIdx[m]]);
    if (t + 1 < NT) STAGE(t + 1);

    __builtin_amdgcn_s_setprio(1);
#pragma unroll
    for (int m = 0; m < 4; ++m)
#pragma unroll
      for (int n = 0; n < 4; ++n)
        acc[m][n] = __builtin_amdgcn_mfma_f32_16x16x32_bf16(af[m], bf[n], acc[m][n], 0, 0, 0);
    __builtin_amdgcn_s_setprio(0);
    // closing barrier is next iteration's WAIT_BAR (or loop exit)
  }
#undef STAGE

  LBAR();  // all slot ds_reads retired; smem reusable as sC

  // LDS-transposed epilogue: per m-chunk, masked acc -> sC[32][SCP] ->
  // full-line nt stores (32 lanes x 16B = 512 B contiguous per row).
  float* sC = reinterpret_cast<float*>(smem);
  float bj[4], rm[4];
#pragma unroll
  for (int n = 0; n < 4; ++n) {
    int col = n0 + wc * 64 + n * 16 + l15;
    bj[n] = bias[col];
    rm[n] = cmask[assign[col]];
  }
#pragma unroll
  for (int m = 0; m < 4; ++m) {
    float4 qm = *reinterpret_cast<const float4*>(&qmask[m0 + wr * 64 + m * 16 + lr * 4]);
    int rl = wr * 16 + lr * 4;  // sC local row
#pragma unroll
    for (int n = 0; n < 4; ++n) {
      int cc = wc * 64 + n * 16 + l15;
      sC[(rl + 0) * SCP + cc] = (acc[m][n][0] + bj[n]) * qm.x * rm[n];
      sC[(rl + 1) * SCP + cc] = (acc[m][n][1] + bj[n]) * qm.y * rm[n];
      sC[(rl + 2) * SCP + cc] = (acc[m][n][2] + bj[n]) * qm.z * rm[n];
      sC[(rl + 3) * SCP + cc] = (acc[m][n][3] + bj[n]) * qm.w * rm[n];
    }
    LBAR();
    f32x4 v[4];
#pragma unroll
    for (int i = 0; i < 4; ++i) {
      int s = wave * 8 + i * 2 + (lane >> 5);
      v[i] = *reinterpret_cast<const f32x4*>(&sC[s * SCP + (lane & 31) * 4]);
    }
    LBAR();
#pragma unroll
    for (int i = 0; i < 4; ++i) {
      int s = wave * 8 + i * 2 + (lane >> 5);
      int grow = m0 + (s >> 4) * 64 + m * 16 + (s & 15);
      __builtin_nontemporal_store(
          v[i], reinterpret_cast<f32x4*>(&C[(size_t)grow * D_OUT + n0 + (lane & 31) * 4]));
    }
  }
}

extern "C" void kernel_launch(void* const* d_in, const int* in_sizes, int n_in,
                              void* d_out, int out_size, void* d_ws, size_t ws_size,
                              hipStream_t stream) {
  const float* input     = (const float*)d_in[0];
  const float* weight    = (const float*)d_in[1];
  const float* bias      = (const float*)d_in[2];
  const float* centroids = (const float*)d_in[3];
  const int*   assign    = (const int*)d_in[4];
  float* out = (float*)d_out;

  // ws layout (bytes):
  //   A_bf16 : 0          (4 MiB)
  //   W_bf16 : 4,194,304  (16 MiB)
  //   qmask  : 20,971,520 (16 KB)
  //   cmask  : 20,987,904 (1 KB)
  //   centT4 : 21,000,192 (512 KB)
  char* ws = (char*)d_ws;
  ushort* A_bf   = (ushort*)ws;
  ushort* W_bf   = (ushort*)(ws + 4194304);
  float*  qmask  = (float*)(ws + 20971520);
  float*  cmask  = (float*)(ws + 20987904);
  float4* centT4 = (float4*)(ws + 21000192);

  prep_kernel<<<4224, 256, 0, stream>>>(weight, W_bf, centroids, centT4, cmask);
  routing_kernel<<<N_Q / 8, 256, 0, stream>>>(input, centT4, qmask, cmask, A_bf);
  gemm_masked_kernel<<<(N_Q / BM) * (D_OUT / BN), 256, 0, stream>>>(
      A_bf, W_bf, bias, assign, qmask, cmask, out);
}

// Round 12
// 152.214 us; speedup vs baseline: 1.7877x; 1.7877x over previous
//
#include <hip/hip_runtime.h>
#include <stdint.h>

#define N_Q    4096
#define D_K    512
#define D_OUT  16384
#define NCLUST 256

// GEMM: 256x256 tile, BK=64, 8 waves (2M x 4N), per-wave 128x64 (acc 8x4).
// 8-phase (4 phases x 2 ks) schedule, 4-slot half-tile piece rings per operand
// (128 KB LDS, 1 WG/CU), counted vmcnt(8) at tile top, raw barriers per phase.
// Piece safety: B(t) retired end-P2 -> stage B(t+2) in P3; A(t) retired end-P3
// -> stage A(t+2) in P4. Swizzle G = kg ^ ((l15>>1)&7), conflict-free.
#define NKT 8          // 512 / 64 K-tiles
#define SCP 260        // sC row stride (floats): 16B-aligned rows, 2-way banks

typedef __attribute__((ext_vector_type(4))) float f32x4;
typedef __attribute__((ext_vector_type(8))) short bf16x8;

__device__ __forceinline__ uint32_t f2bf(float f) {
  uint32_t u = __float_as_uint(f);
  u += 0x7FFFu + ((u >> 16) & 1u);
  return u >> 16;
}

#define GLOAD_LDS16(g, l)                                         \
  __builtin_amdgcn_global_load_lds(                               \
      (const __attribute__((address_space(1))) void*)(g),         \
      (__attribute__((address_space(3))) void*)(l), 16, 0, 0)

#define WAIT_BAR(N) asm volatile("s_waitcnt vmcnt(" #N ")\n\ts_barrier" ::: "memory")
#define BAR()   asm volatile("s_barrier" ::: "memory")
#define LGKM0() asm volatile("s_waitcnt lgkmcnt(0)" ::: "memory")
#define LBAR()  asm volatile("s_waitcnt lgkmcnt(0)\n\ts_barrier" ::: "memory")

// tiny: centroid transpose + cmask zero (must precede routing)
__global__ __launch_bounds__(256) void cent_kernel(const float* __restrict__ cent,
                                                   float4* __restrict__ centT4,
                                                   float* __restrict__ cmask) {
  if (blockIdx.x == 0) cmask[threadIdx.x] = 0.0f;
  int idx = blockIdx.x * 256 + threadIdx.x;
  int k4 = idx & 127, c = idx >> 7;
  float4 v = *reinterpret_cast<const float4*>(&cent[(size_t)c * D_K + k4 * 4]);
  centT4[(size_t)k4 * NCLUST + c] = v;
}

// fat kernel: blocks 0..511 = routing (8 queries/block, fused A convert);
// blocks 512..4607 = W f32->bf16 convert. Independent work -> overlapped.
__global__ __launch_bounds__(256) void fat_kernel(const float* __restrict__ input,
                                                  const float4* __restrict__ centT4,
                                                  float* __restrict__ qmask,
                                                  float* __restrict__ cmask,
                                                  ushort* __restrict__ A_bf,
                                                  const float* __restrict__ weight,
                                                  ushort* __restrict__ W_bf) {
  __shared__ float lgs[8][NCLUST];
  int b = blockIdx.x;
  if (b >= 512) {  // ---- W convert ----
    int i = (b - 512) * 256 + threadIdx.x;
    const float4* s = reinterpret_cast<const float4*>(weight) + (size_t)i * 2;
    float4 v0 = s[0], v1 = s[1];
    uint4 o;
    o.x = f2bf(v0.x) | (f2bf(v0.y) << 16);
    o.y = f2bf(v0.z) | (f2bf(v0.w) << 16);
    o.z = f2bf(v1.x) | (f2bf(v1.y) << 16);
    o.w = f2bf(v1.z) | (f2bf(v1.w) << 16);
    reinterpret_cast<uint4*>(W_bf)[i] = o;
    return;
  }
  // ---- routing (f32 math; threshold booleans must not flip) ----
  int c = threadIdx.x;
  int q0 = b * 8;
  const float* __restrict__ inp = input + (size_t)q0 * D_K;
  {
    const float4* s4 = reinterpret_cast<const float4*>(inp) + c * 4;
    float4 x0 = s4[0], x1 = s4[1], x2 = s4[2], x3 = s4[3];
    uint4 o0, o1;
    o0.x = f2bf(x0.x) | (f2bf(x0.y) << 16);
    o0.y = f2bf(x0.z) | (f2bf(x0.w) << 16);
    o0.z = f2bf(x1.x) | (f2bf(x1.y) << 16);
    o0.w = f2bf(x1.z) | (f2bf(x1.w) << 16);
    o1.x = f2bf(x2.x) | (f2bf(x2.y) << 16);
    o1.y = f2bf(x2.z) | (f2bf(x2.w) << 16);
    o1.z = f2bf(x3.x) | (f2bf(x3.y) << 16);
    o1.w = f2bf(x3.z) | (f2bf(x3.w) << 16);
    uint4* dst = reinterpret_cast<uint4*>(A_bf + (size_t)q0 * D_K);
    dst[c * 2] = o0;
    dst[c * 2 + 1] = o1;
  }
  float acc[8] = {0, 0, 0, 0, 0, 0, 0, 0};
  for (int k4 = 0; k4 < D_K / 4; ++k4) {
    float4 v = centT4[(size_t)k4 * NCLUST + c];
#pragma unroll
    for (int q = 0; q < 8; ++q) {
      float4 r = *reinterpret_cast<const float4*>(&inp[q * D_K + k4 * 4]);
      acc[q] += v.x * r.x + v.y * r.y + v.z * r.z + v.w * r.w;
    }
  }
#pragma unroll
  for (int q = 0; q < 8; ++q) lgs[q][c] = acc[q] * 10.0f;
  __syncthreads();
  int wave = c >> 6, lane = c & 63;
#pragma unroll
  for (int qq = 0; qq < 2; ++qq) {
    int q = wave * 2 + qq;
    float4 lv = *reinterpret_cast<const float4*>(&lgs[q][lane * 4]);
    float m = fmaxf(fmaxf(lv.x, lv.y), fmaxf(lv.z, lv.w));
#pragma unroll
    for (int off = 32; off > 0; off >>= 1) m = fmaxf(m, __shfl_xor(m, off));
    float e0 = expf(lv.x - m), e1 = expf(lv.y - m), e2 = expf(lv.z - m), e3 = expf(lv.w - m);
    float s = e0 + e1 + e2 + e3;
#pragma unroll
    for (int off = 32; off > 0; off >>= 1) s += __shfl_xor(s, off);
    float thr = 0.01f * s;
    bool a0 = e0 > thr, a1 = e1 > thr, a2 = e2 > thr, a3 = e3 > thr;
    if (a0) cmask[lane * 4 + 0] = 1.0f;
    if (a1) cmask[lane * 4 + 1] = 1.0f;
    if (a2) cmask[lane * 4 + 2] = 1.0f;
    if (a3) cmask[lane * 4 + 3] = 1.0f;
    unsigned long long any = __ballot(a0 | a1 | a2 | a3);
    if (lane == 0) qmask[q0 + q] = any ? 1.0f : 0.0f;
  }
}

__global__ __launch_bounds__(512, 2) void gemm_masked_kernel(
    const ushort* __restrict__ A, const ushort* __restrict__ W,
    const float* __restrict__ bias, const int* __restrict__ assign,
    const float* __restrict__ qmask, const float* __restrict__ cmask,
    float* __restrict__ C) {
  // LDS 128 KB: A pieces 4x16K at [0,64K), B pieces 4x16K at [64K,128K).
  // Piece (tile t, half h) -> slot (2t+h)&3. Epilogue reuses [0,66.6K) as sC.
  __shared__ __align__(16) char smem[131072];

  int tid = threadIdx.x;
  int wave = tid >> 6, lane = tid & 63;

  // XCD mapping: xcd=bid&7 owns ntiles [8x,8x+8) (2 MB W L2-panel); 1024%8==0.
  int bid = blockIdx.x;
  int idx = bid >> 3;                       // 0..127
  int ntile = (bid & 7) * 8 + (idx & 7);    // 0..63
  int mtile = idx >> 3;                     // 0..15
  int m0 = mtile * 256, n0 = ntile * 256;

  int wr = wave >> 2, wc = wave & 3;        // per-wave C: 128x64
  int kg0 = lane >> 4, l15 = lane & 15, lr = lane >> 4;

  // staging: thread covers piece rows (tid>>3) and (tid>>3)+64, 16B slot tid&7.
  // LDS[row][G] = global[row][G ^ ((row>>1)&7)] -> src group = (tid&7)^((tid>>4)&7).
  int srcg = (tid & 7) ^ ((tid >> 4) & 7);
  const ushort* srcA = A + (size_t)(m0 + (tid >> 3)) * D_K + srcg * 8;
  const ushort* srcB = W + (size_t)(n0 + (tid >> 3)) * D_K + srcg * 8;
  int dstoff = wave * 1024;  // wave-uniform base; HW adds lane*16

#define STAGE_A(t, h) do {                                                  \
    char* d_ = smem + (((2 * (t) + (h)) & 3) * 16384) + dstoff;             \
    GLOAD_LDS16(srcA + (size_t)((h) * 128) * D_K + (t) * 64, d_);           \
    GLOAD_LDS16(srcA + (size_t)((h) * 128 + 64) * D_K + (t) * 64, d_ + 8192); \
  } while (0)
#define STAGE_B(t, h) do {                                                  \
    char* d_ = smem + 65536 + (((2 * (t) + (h)) & 3) * 16384) + dstoff;     \
    GLOAD_LDS16(srcB + (size_t)((h) * 128) * D_K + (t) * 64, d_);           \
    GLOAD_LDS16(srcB + (size_t)((h) * 128 + 64) * D_K + (t) * 64, d_ + 8192); \
  } while (0)

  // fragment read offsets: addr = piece + fragidx*2048 + kBase[ks]
  // (swizzle f = (l15>>1)&7 is m/n-independent since m*8 ≡ 0 mod 8)
  int fA = (l15 >> 1) & 7;
  int kBase0 = l15 * 128 + ((kg0 ^ fA) << 4);
  int kBase1 = l15 * 128 + (((4 + kg0) ^ fA) << 4);
  int bAdd = (wc & 1) * 8192;  // B piece local rows (wc&1)*64..

  // hoisted epilogue column terms
  float bj[4], rm[4];
#pragma unroll
  for (int n = 0; n < 4; ++n) {
    int col = n0 + wc * 64 + n * 16 + l15;
    bj[n] = bias[col];
    rm[n] = cmask[assign[col]];
  }

  f32x4 acc[8][4] = {};

  // prologue: tiles 0,1 (order B,B,A,A per tile to match steady-state FIFO)
  STAGE_B(0, 0); STAGE_B(0, 1); STAGE_A(0, 0); STAGE_A(0, 1);
  STAGE_B(1, 0); STAGE_B(1, 1); STAGE_A(1, 0); STAGE_A(1, 1);

#pragma unroll
  for (int t = 0; t < NKT; ++t) {
    // tile top: retire tile t's 8 loads; tile t+1's 8 stay in flight.
    if (t < NKT - 1) { WAIT_BAR(8); } else { WAIT_BAR(0); }

    const char* sa = smem + ((2 * t + wr) & 3) * 16384;
    const char* sb = smem + 65536 + ((2 * t + (wc >> 1)) & 3) * 16384 + bAdd;

    bf16x8 a[8], b01[4], b23[4];
    // ---- P1: read A[m0..3], B[n0..1]; MFMA quadrant (m0-3 x n0-1) ----
#pragma unroll
    for (int m = 0; m < 4; ++m) {
      a[m * 2]     = *reinterpret_cast<const bf16x8*>(sa + m * 2048 + kBase0);
      a[m * 2 + 1] = *reinterpret_cast<const bf16x8*>(sa + m * 2048 + kBase1);
    }
#pragma unroll
    for (int n = 0; n < 2; ++n) {
      b01[n * 2]     = *reinterpret_cast<const bf16x8*>(sb + n * 2048 + kBase0);
      b01[n * 2 + 1] = *reinterpret_cast<const bf16x8*>(sb + n * 2048 + kBase1);
    }
    BAR(); LGKM0();
    __builtin_amdgcn_s_setprio(1);
#pragma unroll
    for (int m = 0; m < 4; ++m)
#pragma unroll
      for (int n = 0; n < 2; ++n) {
        acc[m][n] = __builtin_amdgcn_mfma_f32_16x16x32_bf16(a[m * 2], b01[n * 2], acc[m][n], 0, 0, 0);
        acc[m][n] = __builtin_amdgcn_mfma_f32_16x16x32_bf16(a[m * 2 + 1], b01[n * 2 + 1], acc[m][n], 0, 0, 0);
      }
    __builtin_amdgcn_s_setprio(0);
    BAR();
    // ---- P2: read B[n2..3]; MFMA (m0-3 x n2-3) ----
#pragma unroll
    for (int n = 0; n < 2; ++n) {
      b23[n * 2]     = *reinterpret_cast<const bf16x8*>(sb + (2 + n) * 2048 + kBase0);
      b23[n * 2 + 1] = *reinterpret_cast<const bf16x8*>(sb + (2 + n) * 2048 + kBase1);
    }
    BAR(); LGKM0();
    __builtin_amdgcn_s_setprio(1);
#pragma unroll
    for (int m = 0; m < 4; ++m)
#pragma unroll
      for (int n = 0; n < 2; ++n) {
        acc[m][2 + n] = __builtin_amdgcn_mfma_f32_16x16x32_bf16(a[m * 2], b23[n * 2], acc[m][2 + n], 0, 0, 0);
        acc[m][2 + n] = __builtin_amdgcn_mfma_f32_16x16x32_bf16(a[m * 2 + 1], b23[n * 2 + 1], acc[m][2 + n], 0, 0, 0);
      }
    __builtin_amdgcn_s_setprio(0);
    BAR();
    // ---- P3: read A[m4..7]; stage B(t+2) (B(t) retired end-P2); MFMA (m4-7 x n2-3) ----
#pragma unroll
    for (int m = 0; m < 4; ++m) {
      a[m * 2]     = *reinterpret_cast<const bf16x8*>(sa + (4 + m) * 2048 + kBase0);
      a[m * 2 + 1] = *reinterpret_cast<const bf16x8*>(sa + (4 + m) * 2048 + kBase1);
    }
    if (t + 2 < NKT) { STAGE_B(t + 2, 0); STAGE_B(t + 2, 1); }
    BAR(); LGKM0();
    __builtin_amdgcn_s_setprio(1);
#pragma unroll
    for (int m = 0; m < 4; ++m)
#pragma unroll
      for (int n = 0; n < 2; ++n) {
        acc[4 + m][2 + n] = __builtin_amdgcn_mfma_f32_16x16x32_bf16(a[m * 2], b23[n * 2], acc[4 + m][2 + n], 0, 0, 0);
        acc[4 + m][2 + n] = __builtin_amdgcn_mfma_f32_16x16x32_bf16(a[m * 2 + 1], b23[n * 2 + 1], acc[4 + m][2 + n], 0, 0, 0);
      }
    __builtin_amdgcn_s_setprio(0);
    BAR();
    // ---- P4: stage A(t+2) (A(t) retired end-P3); MFMA (m4-7 x n0-1) ----
    if (t + 2 < NKT) { STAGE_A(t + 2, 0); STAGE_A(t + 2, 1); }
    BAR(); LGKM0();
    __builtin_amdgcn_s_setprio(1);
#pragma unroll
    for (int m = 0; m < 4; ++m)
#pragma unroll
      for (int n = 0; n < 2; ++n) {
        acc[4 + m][n] = __builtin_amdgcn_mfma_f32_16x16x32_bf16(a[m * 2], b01[n * 2], acc[4 + m][n], 0, 0, 0);
        acc[4 + m][n] = __builtin_amdgcn_mfma_f32_16x16x32_bf16(a[m * 2 + 1], b01[n * 2 + 1], acc[4 + m][n], 0, 0, 0);
      }
    __builtin_amdgcn_s_setprio(0);
    BAR();
  }
#undef STAGE_A
#undef STAGE_B

  // ---- LDS-transposed epilogue: 4 chunks of 64 rows x 256 cols ----
  float* sC = reinterpret_cast<float*>(smem);
#pragma unroll
  for (int c = 0; c < 4; ++c) {
#pragma unroll
    for (int e = 0; e < 2; ++e) {
      int m = 2 * c + e;
      float4 qm = *reinterpret_cast<const float4*>(&qmask[m0 + wr * 128 + m * 16 + lr * 4]);
      int srow = wr * 32 + e * 16 + lr * 4;
#pragma unroll
      for (int n = 0; n < 4; ++n) {
        int cc = wc * 64 + n * 16 + l15;
        sC[(srow + 0) * SCP + cc] = (acc[m][n][0] + bj[n]) * qm.x * rm[n];
        sC[(srow + 1) * SCP + cc] = (acc[m][n][1] + bj[n]) * qm.y * rm[n];
        sC[(srow + 2) * SCP + cc] = (acc[m][n][2] + bj[n]) * qm.z * rm[n];
        sC[(srow + 3) * SCP + cc] = (acc[m][n][3] + bj[n]) * qm.w * rm[n];
      }
    }
    LBAR();
#pragma unroll
    for (int j = 0; j < 8; ++j) {
      int s = wave * 8 + j;
      f32x4 v = *reinterpret_cast<const f32x4*>(&sC[s * SCP + lane * 4]);
      int grow = m0 + (s >> 5) * 128 + (2 * c + ((s >> 4) & 1)) * 16 + (s & 15);
      __builtin_nontemporal_store(
          v, reinterpret_cast<f32x4*>(&C[(size_t)grow * D_OUT + n0 + lane * 4]));
    }
    LBAR();  // readers done before next chunk overwrites sC
  }
}

extern "C" void kernel_launch(void* const* d_in, const int* in_sizes, int n_in,
                              void* d_out, int out_size, void* d_ws, size_t ws_size,
                              hipStream_t stream) {
  const float* input     = (const float*)d_in[0];
  const float* weight    = (const float*)d_in[1];
  const float* bias      = (const float*)d_in[2];
  const float* centroids = (const float*)d_in[3];
  const int*   assign    = (const int*)d_in[4];
  float* out = (float*)d_out;

  // ws layout (bytes):
  //   A_bf16 : 0          (4 MiB)
  //   W_bf16 : 4,194,304  (16 MiB)
  //   qmask  : 20,971,520 (16 KB)
  //   cmask  : 20,987,904 (1 KB)
  //   centT4 : 21,000,192 (512 KB)
  char* ws = (char*)d_ws;
  ushort* A_bf   = (ushort*)ws;
  ushort* W_bf   = (ushort*)(ws + 4194304);
  float*  qmask  = (float*)(ws + 20971520);
  float*  cmask  = (float*)(ws + 20987904);
  float4* centT4 = (float4*)(ws + 21000192);

  cent_kernel<<<128, 256, 0, stream>>>(centroids, centT4, cmask);
  fat_kernel<<<512 + D_OUT * D_K / 8 / 256, 256, 0, stream>>>(
      input, centT4, qmask, cmask, A_bf, weight, W_bf);
  gemm_masked_kernel<<<(N_Q / 256) * (D_OUT / 256), 512, 0, stream>>>(
      A_bf, W_bf, bias, assign, qmask, cmask, out);
}

// Round 13
// 146.220 us; speedup vs baseline: 1.8610x; 1.0410x over previous
//
#include <hip/hip_runtime.h>
#include <stdint.h>

#define N_Q    4096
#define D_K    512
#define D_OUT  16384
#define NCLUST 256

// GEMM: 128x128 tile, BK=32, 4 waves (2x2), 64x64 per wave.
// Ring-2 LDS (32 KB) + __launch_bounds__(256,4) -> 4 WG/CU (16 waves), VGPR
// cap 128 (76 used, no spill — round-11's (256,5) forced 48+spill per m69's
// 64/128/256 VGPR occupancy steps). m97-style loop (stage t+1 during t, drain
// at tile top); 4 co-resident WGs overlap epilogue C-drains with K-loops (the
// decisive lever at K=512 where C-write ~43us is half the GEMM budget).
// T2 swizzle, setprio, XCD panel mapping, LDS-transposed full-line nt epilogue.
#define BM 128
#define BN 128
#define BK 32
#define NT (D_K / BK)   // 16 K-tiles
#define SCP 132         // sC row stride in floats (non-pow2: conflict-free)

typedef __attribute__((ext_vector_type(4))) float f32x4;
typedef __attribute__((ext_vector_type(8))) short bf16x8;

__device__ __forceinline__ uint32_t f2bf(float f) {
  uint32_t u = __float_as_uint(f);
  u += 0x7FFFu + ((u >> 16) & 1u);
  return u >> 16;
}

#define GLOAD_LDS16(g, l)                                         \
  __builtin_amdgcn_global_load_lds(                               \
      (const __attribute__((address_space(1))) void*)(g),         \
      (__attribute__((address_space(3))) void*)(l), 16, 0, 0)

#define WAIT_BAR(N) asm volatile("s_waitcnt vmcnt(" #N ")\n\ts_barrier" ::: "memory")
#define LBAR() asm volatile("s_waitcnt lgkmcnt(0)\n\ts_barrier" ::: "memory")

// tiny: centroid transpose + cmask zero (must precede routing)
__global__ __launch_bounds__(256) void cent_kernel(const float* __restrict__ cent,
                                                   float4* __restrict__ centT4,
                                                   float* __restrict__ cmask) {
  if (blockIdx.x == 0) cmask[threadIdx.x] = 0.0f;
  int idx = blockIdx.x * 256 + threadIdx.x;
  int k4 = idx & 127, c = idx >> 7;
  float4 v = *reinterpret_cast<const float4*>(&cent[(size_t)c * D_K + k4 * 4]);
  centT4[(size_t)k4 * NCLUST + c] = v;
}

// fat kernel: blocks 0..511 = routing (8 queries/block, fused A convert);
// blocks 512..4607 = W f32->bf16 convert. Independent work -> overlapped.
__global__ __launch_bounds__(256) void fat_kernel(const float* __restrict__ input,
                                                  const float4* __restrict__ centT4,
                                                  float* __restrict__ qmask,
                                                  float* __restrict__ cmask,
                                                  ushort* __restrict__ A_bf,
                                                  const float* __restrict__ weight,
                                                  ushort* __restrict__ W_bf) {
  __shared__ float lgs[8][NCLUST];
  int b = blockIdx.x;
  if (b >= 512) {  // ---- W convert ----
    int i = (b - 512) * 256 + threadIdx.x;
    const float4* s = reinterpret_cast<const float4*>(weight) + (size_t)i * 2;
    float4 v0 = s[0], v1 = s[1];
    uint4 o;
    o.x = f2bf(v0.x) | (f2bf(v0.y) << 16);
    o.y = f2bf(v0.z) | (f2bf(v0.w) << 16);
    o.z = f2bf(v1.x) | (f2bf(v1.y) << 16);
    o.w = f2bf(v1.z) | (f2bf(v1.w) << 16);
    reinterpret_cast<uint4*>(W_bf)[i] = o;
    return;
  }
  // ---- routing (f32 math; threshold booleans must not flip) ----
  int c = threadIdx.x;
  int q0 = b * 8;
  const float* __restrict__ inp = input + (size_t)q0 * D_K;
  {
    const float4* s4 = reinterpret_cast<const float4*>(inp) + c * 4;
    float4 x0 = s4[0], x1 = s4[1], x2 = s4[2], x3 = s4[3];
    uint4 o0, o1;
    o0.x = f2bf(x0.x) | (f2bf(x0.y) << 16);
    o0.y = f2bf(x0.z) | (f2bf(x0.w) << 16);
    o0.z = f2bf(x1.x) | (f2bf(x1.y) << 16);
    o0.w = f2bf(x1.z) | (f2bf(x1.w) << 16);
    o1.x = f2bf(x2.x) | (f2bf(x2.y) << 16);
    o1.y = f2bf(x2.z) | (f2bf(x2.w) << 16);
    o1.z = f2bf(x3.x) | (f2bf(x3.y) << 16);
    o1.w = f2bf(x3.z) | (f2bf(x3.w) << 16);
    uint4* dst = reinterpret_cast<uint4*>(A_bf + (size_t)q0 * D_K);
    dst[c * 2] = o0;
    dst[c * 2 + 1] = o1;
  }
  float acc[8] = {0, 0, 0, 0, 0, 0, 0, 0};
  for (int k4 = 0; k4 < D_K / 4; ++k4) {
    float4 v = centT4[(size_t)k4 * NCLUST + c];
#pragma unroll
    for (int q = 0; q < 8; ++q) {
      float4 r = *reinterpret_cast<const float4*>(&inp[q * D_K + k4 * 4]);  // uniform addr
      acc[q] += v.x * r.x + v.y * r.y + v.z * r.z + v.w * r.w;
    }
  }
#pragma unroll
  for (int q = 0; q < 8; ++q) lgs[q][c] = acc[q] * 10.0f;  // /TEMPERATURE
  __syncthreads();
  int wave = c >> 6, lane = c & 63;
#pragma unroll
  for (int qq = 0; qq < 2; ++qq) {
    int q = wave * 2 + qq;
    float4 lv = *reinterpret_cast<const float4*>(&lgs[q][lane * 4]);
    float m = fmaxf(fmaxf(lv.x, lv.y), fmaxf(lv.z, lv.w));
#pragma unroll
    for (int off = 32; off > 0; off >>= 1) m = fmaxf(m, __shfl_xor(m, off));
    float e0 = expf(lv.x - m), e1 = expf(lv.y - m), e2 = expf(lv.z - m), e3 = expf(lv.w - m);
    float s = e0 + e1 + e2 + e3;
#pragma unroll
    for (int off = 32; off > 0; off >>= 1) s += __shfl_xor(s, off);
    float thr = 0.01f * s;
    bool a0 = e0 > thr, a1 = e1 > thr, a2 = e2 > thr, a3 = e3 > thr;
    if (a0) cmask[lane * 4 + 0] = 1.0f;  // benign races: all writers store 1.0
    if (a1) cmask[lane * 4 + 1] = 1.0f;
    if (a2) cmask[lane * 4 + 2] = 1.0f;
    if (a3) cmask[lane * 4 + 3] = 1.0f;
    unsigned long long any = __ballot(a0 | a1 | a2 | a3);
    if (lane == 0) qmask[q0 + q] = any ? 1.0f : 0.0f;
  }
}

__global__ __launch_bounds__(256, 4) void gemm_masked_kernel(
    const ushort* __restrict__ A, const ushort* __restrict__ W,
    const float* __restrict__ bias, const int* __restrict__ assign,
    const float* __restrict__ qmask, const float* __restrict__ cmask,
    float* __restrict__ C) {
  // LDS 32 KB: 2 slots of 16 KB = {A tile 8K | B tile 8K}. 4 WG/CU.
  // Epilogue reuses the front 16.9 KB as sC[32][SCP] (block-terminal).
  __shared__ __align__(16) char smem[32768];

  int tid = threadIdx.x;
  int wave = tid >> 6, lane = tid & 63;

  // XCD mapping: xcd = bid&7 owns ntiles [16x,16x+16); ntile fast within XCD
  // (2 MB W-set L2-resident); 4096 % 8 == 0 -> bijective.
  int bid = blockIdx.x;
  int idx = bid >> 3;                         // 0..511
  int ntile = (bid & 7) * 16 + (idx & 15);    // 0..127
  int mtile = idx >> 4;                       // 0..31
  int m0 = mtile * BM, n0 = ntile * BN;

  int wr = wave >> 1, wc = wave & 1;  // 2x2 wave grid; per-wave C: 64x64

  // staging: LDS (row,kg) <- global (row, kg ^ ((row>>1)&3)); linear LDS dest,
  // pre-swizzled per-lane source (rule #21). ((64+r)>>1)&3 == ((r>>1)&3) ✓.
  int srow = tid >> 2, kg = tid & 3;
  int ks = (kg ^ ((srow >> 1) & 3)) * 8;
  const ushort* srcA0 = A + (size_t)(m0 + srow) * D_K + ks;       // rows 0..63
  const ushort* srcA1 = srcA0 + (size_t)64 * D_K;                 // rows 64..127
  const ushort* srcB0 = W + (size_t)(n0 + srow) * D_K + ks;
  const ushort* srcB1 = srcB0 + (size_t)64 * D_K;
  int wo = wave << 10;  // wave's 1 KB chunk within each 4 KB op region

#define STAGE(j) do {                                    \
    char* sl_ = smem + ((j) & 1) * 16384 + wo;           \
    GLOAD_LDS16(srcA0 + (j) * BK, sl_);                  \
    GLOAD_LDS16(srcA1 + (j) * BK, sl_ + 4096);           \
    GLOAD_LDS16(srcB0 + (j) * BK, sl_ + 8192);           \
    GLOAD_LDS16(srcB1 + (j) * BK, sl_ + 12288);          \
  } while (0)

  // fragment read indices (swizzled), ushort units within a slot
  int kg0 = lane >> 4, l15 = lane & 15, lr = lane >> 4;
  int aIdx[4], bIdx[4];
#pragma unroll
  for (int m = 0; m < 4; ++m) {
    int r = wr * 64 + m * 16 + l15;
    aIdx[m] = r * 32 + ((kg0 ^ ((r >> 1) & 3)) << 3);
  }
#pragma unroll
  for (int n = 0; n < 4; ++n) {
    int r = wc * 64 + n * 16 + l15;
    bIdx[n] = 4096 + r * 32 + ((kg0 ^ ((r >> 1) & 3)) << 3);  // B at +8 KB
  }

  f32x4 acc[4][4] = {};

  STAGE(0);

#pragma unroll
  for (int t = 0; t < NT; ++t) {
    // loop top: drain tile t's 4 loads (issued last iter; residual latency
    // covered by 16-wave TLP). Barrier also retires slot (t+1)&1's ds_reads
    // from iter t-1 before STAGE(t+1) overwrites it.
    WAIT_BAR(0);

    const ushort* sl = (const ushort*)(smem + (t & 1) * 16384);
    bf16x8 af[4], bf[4];
#pragma unroll
    for (int n = 0; n < 4; ++n) bf[n] = *reinterpret_cast<const bf16x8*>(&sl[bIdx[n]]);
#pragma unroll
    for (int m = 0; m < 4; ++m) af[m] = *reinterpret_cast<const bf16x8*>(&sl[aIdx[m]]);
    if (t + 1 < NT) STAGE(t + 1);

    __builtin_amdgcn_s_setprio(1);
#pragma unroll
    for (int m = 0; m < 4; ++m)
#pragma unroll
      for (int n = 0; n < 4; ++n)
        acc[m][n] = __builtin_amdgcn_mfma_f32_16x16x32_bf16(af[m], bf[n], acc[m][n], 0, 0, 0);
    __builtin_amdgcn_s_setprio(0);
    // closing barrier is next iteration's WAIT_BAR (or loop exit)
  }
#undef STAGE

  LBAR();  // all slot ds_reads retired; smem reusable as sC

  // LDS-transposed epilogue: per m-chunk, masked acc -> sC[32][SCP] ->
  // full-line nt stores (32 lanes x 16B = 512 B contiguous per row).
  float* sC = reinterpret_cast<float*>(smem);
  float bj[4], rm[4];
#pragma unroll
  for (int n = 0; n < 4; ++n) {
    int col = n0 + wc * 64 + n * 16 + l15;
    bj[n] = bias[col];
    rm[n] = cmask[assign[col]];
  }
#pragma unroll
  for (int m = 0; m < 4; ++m) {
    float4 qm = *reinterpret_cast<const float4*>(&qmask[m0 + wr * 64 + m * 16 + lr * 4]);
    int rl = wr * 16 + lr * 4;  // sC local row
#pragma unroll
    for (int n = 0; n < 4; ++n) {
      int cc = wc * 64 + n * 16 + l15;
      sC[(rl + 0) * SCP + cc] = (acc[m][n][0] + bj[n]) * qm.x * rm[n];
      sC[(rl + 1) * SCP + cc] = (acc[m][n][1] + bj[n]) * qm.y * rm[n];
      sC[(rl + 2) * SCP + cc] = (acc[m][n][2] + bj[n]) * qm.z * rm[n];
      sC[(rl + 3) * SCP + cc] = (acc[m][n][3] + bj[n]) * qm.w * rm[n];
    }
    LBAR();
    f32x4 v[4];
#pragma unroll
    for (int i = 0; i < 4; ++i) {
      int s = wave * 8 + i * 2 + (lane >> 5);
      v[i] = *reinterpret_cast<const f32x4*>(&sC[s * SCP + (lane & 31) * 4]);
    }
    LBAR();
#pragma unroll
    for (int i = 0; i < 4; ++i) {
      int s = wave * 8 + i * 2 + (lane >> 5);
      int grow = m0 + (s >> 4) * 64 + m * 16 + (s & 15);
      __builtin_nontemporal_store(
          v[i], reinterpret_cast<f32x4*>(&C[(size_t)grow * D_OUT + n0 + (lane & 31) * 4]));
    }
  }
}

extern "C" void kernel_launch(void* const* d_in, const int* in_sizes, int n_in,
                              void* d_out, int out_size, void* d_ws, size_t ws_size,
                              hipStream_t stream) {
  const float* input     = (const float*)d_in[0];
  const float* weight    = (const float*)d_in[1];
  const float* bias      = (const float*)d_in[2];
  const float* centroids = (const float*)d_in[3];
  const int*   assign    = (const int*)d_in[4];
  float* out = (float*)d_out;

  // ws layout (bytes):
  //   A_bf16 : 0          (4 MiB)
  //   W_bf16 : 4,194,304  (16 MiB)
  //   qmask  : 20,971,520 (16 KB)
  //   cmask  : 20,987,904 (1 KB)
  //   centT4 : 21,000,192 (512 KB)
  char* ws = (char*)d_ws;
  ushort* A_bf   = (ushort*)ws;
  ushort* W_bf   = (ushort*)(ws + 4194304);
  float*  qmask  = (float*)(ws + 20971520);
  float*  cmask  = (float*)(ws + 20987904);
  float4* centT4 = (float4*)(ws + 21000192);

  cent_kernel<<<128, 256, 0, stream>>>(centroids, centT4, cmask);
  fat_kernel<<<512 + D_OUT * D_K / 8 / 256, 256, 0, stream>>>(
      input, centT4, qmask, cmask, A_bf, weight, W_bf);
  gemm_masked_kernel<<<(N_Q / BM) * (D_OUT / BN), 256, 0, stream>>>(
      A_bf, W_bf, bias, assign, qmask, cmask, out);
}

// Round 14
// 139.561 us; speedup vs baseline: 1.9498x; 1.0477x over previous
//
#include <hip/hip_runtime.h>
#include <stdint.h>

#define N_Q    4096
#define D_K    512
#define D_OUT  16384
#define NCLUST 256

// GEMM: round-8 structure verbatim (best: 133us total) — 128x128 tile, BK=32,
// 4 waves (2x2), 64x64/wave, ring-3 LDS (48 KB) -> 3 WG/CU, counted WAIT_BAR(4)
// (distance-2 prefetch, never drains mid-loop; the r8/r11/r13 ladder showed
// counted-vmcnt > +1 WG), T2 swizzle, setprio, XCD panel mapping,
// LDS-transposed full-line nt epilogue (SCP=132).
// Front-end: round-13 fused cent+fat (W-convert overlaps routing, ~7us).
#define BM 128
#define BN 128
#define BK 32
#define NT (D_K / BK)   // 16 K-tiles
#define SCP 132         // sC row stride in floats (non-pow2: conflict-free)

typedef __attribute__((ext_vector_type(4))) float f32x4;
typedef __attribute__((ext_vector_type(8))) short bf16x8;

__device__ __forceinline__ uint32_t f2bf(float f) {
  uint32_t u = __float_as_uint(f);
  u += 0x7FFFu + ((u >> 16) & 1u);
  return u >> 16;
}

#define GLOAD_LDS16(g, l)                                         \
  __builtin_amdgcn_global_load_lds(                               \
      (const __attribute__((address_space(1))) void*)(g),         \
      (__attribute__((address_space(3))) void*)(l), 16, 0, 0)

#define WAIT_BAR(N) asm volatile("s_waitcnt vmcnt(" #N ")\n\ts_barrier" ::: "memory")
#define LBAR() asm volatile("s_waitcnt lgkmcnt(0)\n\ts_barrier" ::: "memory")

// tiny: centroid transpose + cmask zero (must precede routing)
__global__ __launch_bounds__(256) void cent_kernel(const float* __restrict__ cent,
                                                   float4* __restrict__ centT4,
                                                   float* __restrict__ cmask) {
  if (blockIdx.x == 0) cmask[threadIdx.x] = 0.0f;
  int idx = blockIdx.x * 256 + threadIdx.x;
  int k4 = idx & 127, c = idx >> 7;
  float4 v = *reinterpret_cast<const float4*>(&cent[(size_t)c * D_K + k4 * 4]);
  centT4[(size_t)k4 * NCLUST + c] = v;
}

// fat kernel: blocks 0..511 = routing (8 queries/block, fused A convert);
// blocks 512..4607 = W f32->bf16 convert. Independent work -> overlapped.
__global__ __launch_bounds__(256) void fat_kernel(const float* __restrict__ input,
                                                  const float4* __restrict__ centT4,
                                                  float* __restrict__ qmask,
                                                  float* __restrict__ cmask,
                                                  ushort* __restrict__ A_bf,
                                                  const float* __restrict__ weight,
                                                  ushort* __restrict__ W_bf) {
  __shared__ float lgs[8][NCLUST];
  int b = blockIdx.x;
  if (b >= 512) {  // ---- W convert ----
    int i = (b - 512) * 256 + threadIdx.x;
    const float4* s = reinterpret_cast<const float4*>(weight) + (size_t)i * 2;
    float4 v0 = s[0], v1 = s[1];
    uint4 o;
    o.x = f2bf(v0.x) | (f2bf(v0.y) << 16);
    o.y = f2bf(v0.z) | (f2bf(v0.w) << 16);
    o.z = f2bf(v1.x) | (f2bf(v1.y) << 16);
    o.w = f2bf(v1.z) | (f2bf(v1.w) << 16);
    reinterpret_cast<uint4*>(W_bf)[i] = o;
    return;
  }
  // ---- routing (f32 math; threshold booleans must not flip) ----
  int c = threadIdx.x;
  int q0 = b * 8;
  const float* __restrict__ inp = input + (size_t)q0 * D_K;
  {
    const float4* s4 = reinterpret_cast<const float4*>(inp) + c * 4;
    float4 x0 = s4[0], x1 = s4[1], x2 = s4[2], x3 = s4[3];
    uint4 o0, o1;
    o0.x = f2bf(x0.x) | (f2bf(x0.y) << 16);
    o0.y = f2bf(x0.z) | (f2bf(x0.w) << 16);
    o0.z = f2bf(x1.x) | (f2bf(x1.y) << 16);
    o0.w = f2bf(x1.z) | (f2bf(x1.w) << 16);
    o1.x = f2bf(x2.x) | (f2bf(x2.y) << 16);
    o1.y = f2bf(x2.z) | (f2bf(x2.w) << 16);
    o1.z = f2bf(x3.x) | (f2bf(x3.y) << 16);
    o1.w = f2bf(x3.z) | (f2bf(x3.w) << 16);
    uint4* dst = reinterpret_cast<uint4*>(A_bf + (size_t)q0 * D_K);
    dst[c * 2] = o0;
    dst[c * 2 + 1] = o1;
  }
  float acc[8] = {0, 0, 0, 0, 0, 0, 0, 0};
  for (int k4 = 0; k4 < D_K / 4; ++k4) {
    float4 v = centT4[(size_t)k4 * NCLUST + c];
#pragma unroll
    for (int q = 0; q < 8; ++q) {
      float4 r = *reinterpret_cast<const float4*>(&inp[q * D_K + k4 * 4]);  // uniform addr
      acc[q] += v.x * r.x + v.y * r.y + v.z * r.z + v.w * r.w;
    }
  }
#pragma unroll
  for (int q = 0; q < 8; ++q) lgs[q][c] = acc[q] * 10.0f;  // /TEMPERATURE
  __syncthreads();
  int wave = c >> 6, lane = c & 63;
#pragma unroll
  for (int qq = 0; qq < 2; ++qq) {
    int q = wave * 2 + qq;
    float4 lv = *reinterpret_cast<const float4*>(&lgs[q][lane * 4]);
    float m = fmaxf(fmaxf(lv.x, lv.y), fmaxf(lv.z, lv.w));
#pragma unroll
    for (int off = 32; off > 0; off >>= 1) m = fmaxf(m, __shfl_xor(m, off));
    float e0 = expf(lv.x - m), e1 = expf(lv.y - m), e2 = expf(lv.z - m), e3 = expf(lv.w - m);
    float s = e0 + e1 + e2 + e3;
#pragma unroll
    for (int off = 32; off > 0; off >>= 1) s += __shfl_xor(s, off);
    float thr = 0.01f * s;
    bool a0 = e0 > thr, a1 = e1 > thr, a2 = e2 > thr, a3 = e3 > thr;
    if (a0) cmask[lane * 4 + 0] = 1.0f;  // benign races: all writers store 1.0
    if (a1) cmask[lane * 4 + 1] = 1.0f;
    if (a2) cmask[lane * 4 + 2] = 1.0f;
    if (a3) cmask[lane * 4 + 3] = 1.0f;
    unsigned long long any = __ballot(a0 | a1 | a2 | a3);
    if (lane == 0) qmask[q0 + q] = any ? 1.0f : 0.0f;
  }
}

__global__ __launch_bounds__(256, 3) void gemm_masked_kernel(
    const ushort* __restrict__ A, const ushort* __restrict__ W,
    const float* __restrict__ bias, const int* __restrict__ assign,
    const float* __restrict__ qmask, const float* __restrict__ cmask,
    float* __restrict__ C) {
  // LDS 48 KB: slot j at j*16K = {A tile 8K | B tile 8K}. Epilogue reuses
  // the front 16.9 KB as sC[32][SCP] after the K-loop (block-terminal).
  __shared__ __align__(16) char smem[49152];

  int tid = threadIdx.x;
  int wave = tid >> 6, lane = tid & 63;

  // XCD mapping: xcd = bid&7 owns ntiles [16x,16x+16); ntile fast within XCD
  // (2 MB W-set L2-resident); 4096 % 8 == 0 -> bijective.
  int bid = blockIdx.x;
  int idx = bid >> 3;                         // 0..511
  int ntile = (bid & 7) * 16 + (idx & 15);    // 0..127
  int mtile = idx >> 4;                       // 0..31
  int m0 = mtile * BM, n0 = ntile * BN;

  int wr = wave >> 1, wc = wave & 1;  // 2x2 wave grid; per-wave C: 64x64

  // staging: LDS (row,kg) <- global (row, kg ^ ((row>>1)&3)); linear LDS dest,
  // pre-swizzled per-lane source (rule #21). ((64+r)>>1)&3 == ((r>>1)&3) ✓.
  int srow = tid >> 2, kg = tid & 3;
  int ks = (kg ^ ((srow >> 1) & 3)) * 8;
  const ushort* srcA0 = A + (size_t)(m0 + srow) * D_K + ks;       // rows 0..63
  const ushort* srcA1 = srcA0 + (size_t)64 * D_K;                 // rows 64..127
  const ushort* srcB0 = W + (size_t)(n0 + srow) * D_K + ks;
  const ushort* srcB1 = srcB0 + (size_t)64 * D_K;
  int wo = wave << 10;  // wave's 1 KB chunk within each 4 KB op region

#define STAGE(j) do {                                    \
    char* sl_ = smem + ((j) % 3) * 16384 + wo;           \
    GLOAD_LDS16(srcA0 + (j) * BK, sl_);                  \
    GLOAD_LDS16(srcA1 + (j) * BK, sl_ + 4096);           \
    GLOAD_LDS16(srcB0 + (j) * BK, sl_ + 8192);           \
    GLOAD_LDS16(srcB1 + (j) * BK, sl_ + 12288);          \
  } while (0)

  // fragment read indices (swizzled), ushort units within a slot
  int kg0 = lane >> 4, l15 = lane & 15, lr = lane >> 4;
  int aIdx[4], bIdx[4];
#pragma unroll
  for (int m = 0; m < 4; ++m) {
    int r = wr * 64 + m * 16 + l15;
    aIdx[m] = r * 32 + ((kg0 ^ ((r >> 1) & 3)) << 3);
  }
#pragma unroll
  for (int n = 0; n < 4; ++n) {
    int r = wc * 64 + n * 16 + l15;
    bIdx[n] = 4096 + r * 32 + ((kg0 ^ ((r >> 1) & 3)) << 3);  // B at +8 KB
  }

  f32x4 acc[4][4] = {};

  STAGE(0);
  STAGE(1);

#pragma unroll
  for (int t = 0; t < NT; ++t) {
    // loop top: tile t's 4 loads are oldest; tile t+1's 4 stay in flight.
    if (t < NT - 1) { WAIT_BAR(4); } else { WAIT_BAR(0); }

    const ushort* sl = (const ushort*)(smem + (t % 3) * 16384);
    bf16x8 af[4], bf[4];
#pragma unroll
    for (int n = 0; n < 4; ++n) bf[n] = *reinterpret_cast<const bf16x8*>(&sl[bIdx[n]]);
#pragma unroll
    for (int m = 0; m < 4; ++m) af[m] = *reinterpret_cast<const bf16x8*>(&sl[aIdx[m]]);
    if (t + 2 < NT) STAGE(t + 2);  // slot (t+2)%3 == (t-1)%3: reads retired pre-barrier

    __builtin_amdgcn_s_setprio(1);
#pragma unroll
    for (int m = 0; m < 4; ++m)
#pragma unroll
      for (int n = 0; n < 4; ++n)
        acc[m][n] = __builtin_amdgcn_mfma_f32_16x16x32_bf16(af[m], bf[n], acc[m][n], 0, 0, 0);
    __builtin_amdgcn_s_setprio(0);
    // closing barrier is next iteration's WAIT_BAR (or loop exit)
  }
#undef STAGE

  LBAR();  // all slot ds_reads retired; smem reusable as sC

  // LDS-transposed epilogue: per m-chunk, masked acc -> sC[32][SCP] ->
  // full-line nt stores (32 lanes x 16B = 512 B contiguous per row).
  float* sC = reinterpret_cast<float*>(smem);
  float bj[4], rm[4];
#pragma unroll
  for (int n = 0; n < 4; ++n) {
    int col = n0 + wc * 64 + n * 16 + l15;
    bj[n] = bias[col];
    rm[n] = cmask[assign[col]];
  }
#pragma unroll
  for (int m = 0; m < 4; ++m) {
    float4 qm = *reinterpret_cast<const float4*>(&qmask[m0 + wr * 64 + m * 16 + lr * 4]);
    int rl = wr * 16 + lr * 4;  // sC local row
#pragma unroll
    for (int n = 0; n < 4; ++n) {
      int cc = wc * 64 + n * 16 + l15;
      sC[(rl + 0) * SCP + cc] = (acc[m][n][0] + bj[n]) * qm.x * rm[n];
      sC[(rl + 1) * SCP + cc] = (acc[m][n][1] + bj[n]) * qm.y * rm[n];
      sC[(rl + 2) * SCP + cc] = (acc[m][n][2] + bj[n]) * qm.z * rm[n];
      sC[(rl + 3) * SCP + cc] = (acc[m][n][3] + bj[n]) * qm.w * rm[n];
    }
    LBAR();
    f32x4 v[4];
#pragma unroll
    for (int i = 0; i < 4; ++i) {
      int s = wave * 8 + i * 2 + (lane >> 5);
      v[i] = *reinterpret_cast<const f32x4*>(&sC[s * SCP + (lane & 31) * 4]);
    }
    LBAR();
#pragma unroll
    for (int i = 0; i < 4; ++i) {
      int s = wave * 8 + i * 2 + (lane >> 5);
      int grow = m0 + (s >> 4) * 64 + m * 16 + (s & 15);
      __builtin_nontemporal_store(
          v[i], reinterpret_cast<f32x4*>(&C[(size_t)grow * D_OUT + n0 + (lane & 31) * 4]));
    }
  }
}

extern "C" void kernel_launch(void* const* d_in, const int* in_sizes, int n_in,
                              void* d_out, int out_size, void* d_ws, size_t ws_size,
                              hipStream_t stream) {
  const float* input     = (const float*)d_in[0];
  const float* weight    = (const float*)d_in[1];
  const float* bias      = (const float*)d_in[2];
  const float* centroids = (const float*)d_in[3];
  const int*   assign    = (const int*)d_in[4];
  float* out = (float*)d_out;

  // ws layout (bytes):
  //   A_bf16 : 0          (4 MiB)
  //   W_bf16 : 4,194,304  (16 MiB)
  //   qmask  : 20,971,520 (16 KB)
  //   cmask  : 20,987,904 (1 KB)
  //   centT4 : 21,000,192 (512 KB)
  char* ws = (char*)d_ws;
  ushort* A_bf   = (ushort*)ws;
  ushort* W_bf   = (ushort*)(ws + 4194304);
  float*  qmask  = (float*)(ws + 20971520);
  float*  cmask  = (float*)(ws + 20987904);
  float4* centT4 = (float4*)(ws + 21000192);

  cent_kernel<<<128, 256, 0, stream>>>(centroids, centT4, cmask);
  fat_kernel<<<512 + D_OUT * D_K / 8 / 256, 256, 0, stream>>>(
      input, centT4, qmask, cmask, A_bf, weight, W_bf);
  gemm_masked_kernel<<<(N_Q / BM) * (D_OUT / BN), 256, 0, stream>>>(
      A_bf, W_bf, bias, assign, qmask, cmask, out);
}

// Round 15
// 133.031 us; speedup vs baseline: 2.0455x; 1.0491x over previous
//
#include <hip/hip_runtime.h>
#include <stdint.h>

#define N_Q    4096
#define D_K    512
#define D_OUT  16384
#define NCLUST 256

// GEMM: 256x128 tile, BK=32, 4 waves (2M x 2N), per-wave 128x64 (acc 8x4).
// Round-15 lever: LDS bytes/MAC. Round-8's 64x64 waves move 4.8 GB of LDS
// (~69us at 69TB/s = the dominant pipe; MfmaUtil 17%/VALU 11%/HBM 25% all idle).
// 128x64 waves cut read traffic (1/BMw+1/BNw) by 25% and staging by 25%:
// 2.5 GB (~37us). Ring-3 slots of 24 KB = 72 KB -> 2 WG/CU keeps BOTH proven
// levers: counted WAIT_BAR(6) (never drains mid-loop) + multi-WG drain overlap.
// launch_bounds(256,2) -> 256-VGPR cap (est ~200, no spill).
// Front-end: round-8 serial prep+routing (fused variant measured 6.5us slower).
#define BM 256
#define BN 128
#define BK 32
#define NT (D_K / BK)   // 16 K-tiles
#define SCP 132         // sC row stride in floats (non-pow2: conflict-free)

typedef __attribute__((ext_vector_type(4))) float f32x4;
typedef __attribute__((ext_vector_type(8))) short bf16x8;

__device__ __forceinline__ uint32_t f2bf(float f) {
  uint32_t u = __float_as_uint(f);
  u += 0x7FFFu + ((u >> 16) & 1u);
  return u >> 16;
}

#define GLOAD_LDS16(g, l)                                         \
  __builtin_amdgcn_global_load_lds(                               \
      (const __attribute__((address_space(1))) void*)(g),         \
      (__attribute__((address_space(3))) void*)(l), 16, 0, 0)

#define WAIT_BAR(N) asm volatile("s_waitcnt vmcnt(" #N ")\n\ts_barrier" ::: "memory")
#define LBAR() asm volatile("s_waitcnt lgkmcnt(0)\n\ts_barrier" ::: "memory")

// merged: W f32->bf16 convert (blocks 0..4095) + centroid transpose (4096..4223)
__global__ __launch_bounds__(256) void prep_kernel(const float* __restrict__ weight,
                                                   ushort* __restrict__ W_bf,
                                                   const float* __restrict__ cent,
                                                   float4* __restrict__ centT4,
                                                   float* __restrict__ cmask) {
  int b = blockIdx.x;
  if (b < (D_OUT * D_K / 8) / 256) {
    int i = b * 256 + threadIdx.x;
    const float4* s = reinterpret_cast<const float4*>(weight) + (size_t)i * 2;
    float4 v0 = s[0], v1 = s[1];
    uint4 o;
    o.x = f2bf(v0.x) | (f2bf(v0.y) << 16);
    o.y = f2bf(v0.z) | (f2bf(v0.w) << 16);
    o.z = f2bf(v1.x) | (f2bf(v1.y) << 16);
    o.w = f2bf(v1.z) | (f2bf(v1.w) << 16);
    reinterpret_cast<uint4*>(W_bf)[i] = o;
  } else {
    int bb = b - (D_OUT * D_K / 8) / 256;
    if (bb == 0) cmask[threadIdx.x] = 0.0f;
    int idx = bb * 256 + threadIdx.x;
    int k4 = idx & 127, c = idx >> 7;
    float4 v = *reinterpret_cast<const float4*>(&cent[(size_t)c * D_K + k4 * 4]);
    centT4[(size_t)k4 * NCLUST + c] = v;
  }
}

// 8 queries/block; thread t owns centroid t; fused A f32->bf16 convert.
// f32 routing math throughout (threshold booleans must not flip).
__global__ __launch_bounds__(256) void routing_kernel(const float* __restrict__ input,
                                                      const float4* __restrict__ centT4,
                                                      float* __restrict__ qmask,
                                                      float* __restrict__ cmask,
                                                      ushort* __restrict__ A_bf) {
  __shared__ float lgs[8][NCLUST];
  int c = threadIdx.x;
  int q0 = blockIdx.x * 8;
  const float* __restrict__ inp = input + (size_t)q0 * D_K;

  {
    const float4* s4 = reinterpret_cast<const float4*>(inp) + c * 4;
    float4 x0 = s4[0], x1 = s4[1], x2 = s4[2], x3 = s4[3];
    uint4 o0, o1;
    o0.x = f2bf(x0.x) | (f2bf(x0.y) << 16);
    o0.y = f2bf(x0.z) | (f2bf(x0.w) << 16);
    o0.z = f2bf(x1.x) | (f2bf(x1.y) << 16);
    o0.w = f2bf(x1.z) | (f2bf(x1.w) << 16);
    o1.x = f2bf(x2.x) | (f2bf(x2.y) << 16);
    o1.y = f2bf(x2.z) | (f2bf(x2.w) << 16);
    o1.z = f2bf(x3.x) | (f2bf(x3.y) << 16);
    o1.w = f2bf(x3.z) | (f2bf(x3.w) << 16);
    uint4* dst = reinterpret_cast<uint4*>(A_bf + (size_t)q0 * D_K);
    dst[c * 2] = o0;
    dst[c * 2 + 1] = o1;
  }

  float acc[8] = {0, 0, 0, 0, 0, 0, 0, 0};
  for (int k4 = 0; k4 < D_K / 4; ++k4) {
    float4 v = centT4[(size_t)k4 * NCLUST + c];
#pragma unroll
    for (int q = 0; q < 8; ++q) {
      float4 r = *reinterpret_cast<const float4*>(&inp[q * D_K + k4 * 4]);  // uniform addr
      acc[q] += v.x * r.x + v.y * r.y + v.z * r.z + v.w * r.w;
    }
  }
#pragma unroll
  for (int q = 0; q < 8; ++q) lgs[q][c] = acc[q] * 10.0f;  // /TEMPERATURE
  __syncthreads();

  int wave = c >> 6, lane = c & 63;
#pragma unroll
  for (int qq = 0; qq < 2; ++qq) {
    int q = wave * 2 + qq;
    float4 lv = *reinterpret_cast<const float4*>(&lgs[q][lane * 4]);
    float m = fmaxf(fmaxf(lv.x, lv.y), fmaxf(lv.z, lv.w));
#pragma unroll
    for (int off = 32; off > 0; off >>= 1) m = fmaxf(m, __shfl_xor(m, off));
    float e0 = expf(lv.x - m), e1 = expf(lv.y - m), e2 = expf(lv.z - m), e3 = expf(lv.w - m);
    float s = e0 + e1 + e2 + e3;
#pragma unroll
    for (int off = 32; off > 0; off >>= 1) s += __shfl_xor(s, off);
    float thr = 0.01f * s;
    bool a0 = e0 > thr, a1 = e1 > thr, a2 = e2 > thr, a3 = e3 > thr;
    if (a0) cmask[lane * 4 + 0] = 1.0f;  // benign races: all writers store 1.0
    if (a1) cmask[lane * 4 + 1] = 1.0f;
    if (a2) cmask[lane * 4 + 2] = 1.0f;
    if (a3) cmask[lane * 4 + 3] = 1.0f;
    unsigned long long any = __ballot(a0 | a1 | a2 | a3);
    if (lane == 0) qmask[q0 + q] = any ? 1.0f : 0.0f;
  }
}

__global__ __launch_bounds__(256, 2) void gemm_masked_kernel(
    const ushort* __restrict__ A, const ushort* __restrict__ W,
    const float* __restrict__ bias, const int* __restrict__ assign,
    const float* __restrict__ qmask, const float* __restrict__ cmask,
    float* __restrict__ C) {
  // LDS 72 KB: 3 slots of 24 KB = {A 16 KB (4 x 4KB row-groups) | B 8 KB}.
  // Epilogue reuses front 33.8 KB as sC[64][SCP]. 2 WG/CU.
  __shared__ __align__(16) char smem[73728];

  int tid = threadIdx.x;
  int wave = tid >> 6, lane = tid & 63;

  // XCD mapping: xcd = bid&7 owns ntiles [16x,16x+16); ntile fast within XCD
  // (2 MB W-set L2-resident). 2048 = 8*16*16 -> bijective.
  int bid = blockIdx.x;
  int idx = bid >> 3;                         // 0..255
  int ntile = (bid & 7) * 16 + (idx & 15);    // 0..127
  int mtile = idx >> 4;                       // 0..15
  int m0 = mtile * BM, n0 = ntile * BN;

  int wr = wave >> 1, wc = wave & 1;  // 2x2 wave grid; per-wave C: 128x64

  // staging: LDS (row,kg) <- global (row, kg ^ ((row>>1)&3)); linear LDS dest,
  // pre-swizzled per-lane source (rule #21). ((64p+r)>>1)&3 == ((r>>1)&3) ✓.
  int srow = tid >> 2, kg = tid & 3;
  int ks = (kg ^ ((srow >> 1) & 3)) * 8;
  const ushort* srcA = A + (size_t)(m0 + srow) * D_K + ks;   // + 64p rows, p=0..3
  const ushort* srcB = W + (size_t)(n0 + srow) * D_K + ks;   // + 64p rows, p=0..1
  int wo = wave << 10;  // wave's 1 KB chunk within each 4 KB row-group

#define STAGE(j) do {                                                    \
    char* sl_ = smem + ((j) % 3) * 24576 + wo;                           \
    GLOAD_LDS16(srcA + (j) * BK, sl_);                                   \
    GLOAD_LDS16(srcA + (size_t)64 * D_K + (j) * BK, sl_ + 4096);         \
    GLOAD_LDS16(srcA + (size_t)128 * D_K + (j) * BK, sl_ + 8192);        \
    GLOAD_LDS16(srcA + (size_t)192 * D_K + (j) * BK, sl_ + 12288);       \
    GLOAD_LDS16(srcB + (j) * BK, sl_ + 16384);                           \
    GLOAD_LDS16(srcB + (size_t)64 * D_K + (j) * BK, sl_ + 20480);        \
  } while (0)

  // fragment read indices (swizzled), ushort units within a slot.
  // A rows r=0..255 are LINEAR at r*32 (64 rows per 4 KB group, packed).
  int kg0 = lane >> 4, l15 = lane & 15, lr = lane >> 4;
  int aIdx[8], bIdx[4];
#pragma unroll
  for (int m = 0; m < 8; ++m) {
    int r = wr * 128 + m * 16 + l15;
    aIdx[m] = r * 32 + ((kg0 ^ ((r >> 1) & 3)) << 3);
  }
#pragma unroll
  for (int n = 0; n < 4; ++n) {
    int r = wc * 64 + n * 16 + l15;
    bIdx[n] = 8192 + r * 32 + ((kg0 ^ ((r >> 1) & 3)) << 3);  // B at +16 KB
  }

  f32x4 acc[8][4] = {};

  STAGE(0);
  STAGE(1);

#pragma unroll
  for (int t = 0; t < NT; ++t) {
    // loop top: tile t's 6 loads are oldest (12 outstanding with t+1's 6);
    // WAIT_BAR(6) retires exactly tile t, t+1 stays in flight.
    if (t < NT - 1) { WAIT_BAR(6); } else { WAIT_BAR(0); }

    const ushort* sl = (const ushort*)(smem + (t % 3) * 24576);
    bf16x8 af[8], bf[4];
#pragma unroll
    for (int n = 0; n < 4; ++n) bf[n] = *reinterpret_cast<const bf16x8*>(&sl[bIdx[n]]);
#pragma unroll
    for (int m = 0; m < 8; ++m) af[m] = *reinterpret_cast<const bf16x8*>(&sl[aIdx[m]]);
    if (t + 2 < NT) STAGE(t + 2);  // slot (t+2)%3 == (t-1)%3: reads retired pre-barrier

    __builtin_amdgcn_s_setprio(1);
#pragma unroll
    for (int m = 0; m < 8; ++m)
#pragma unroll
      for (int n = 0; n < 4; ++n)
        acc[m][n] = __builtin_amdgcn_mfma_f32_16x16x32_bf16(af[m], bf[n], acc[m][n], 0, 0, 0);
    __builtin_amdgcn_s_setprio(0);
    // closing barrier is next iteration's WAIT_BAR (or loop exit)
  }
#undef STAGE

  LBAR();  // all slot ds_reads retired; smem reusable as sC

  // LDS-transposed epilogue: 4 super-chunks of 64 rows x 128 cols via
  // sC[64][SCP]; full-line nt stores (32 lanes x 16B = 512 B/row-half).
  // Chunk s covers m-frags {2s, 2s+1} of BOTH wr halves (rows wr*128+s*32+..).
  float* sC = reinterpret_cast<float*>(smem);
  float bj[4], rm[4];
#pragma unroll
  for (int n = 0; n < 4; ++n) {
    int col = n0 + wc * 64 + n * 16 + l15;
    bj[n] = bias[col];
    rm[n] = cmask[assign[col]];
  }
#pragma unroll
  for (int s = 0; s < 4; ++s) {
#pragma unroll
    for (int e = 0; e < 2; ++e) {
      int m = 2 * s + e;
      float4 qm = *reinterpret_cast<const float4*>(&qmask[m0 + wr * 128 + m * 16 + lr * 4]);
      int rl = wr * 32 + e * 16 + lr * 4;  // sC local row
#pragma unroll
      for (int n = 0; n < 4; ++n) {
        int cc = wc * 64 + n * 16 + l15;
        sC[(rl + 0) * SCP + cc] = (acc[m][n][0] + bj[n]) * qm.x * rm[n];
        sC[(rl + 1) * SCP + cc] = (acc[m][n][1] + bj[n]) * qm.y * rm[n];
        sC[(rl + 2) * SCP + cc] = (acc[m][n][2] + bj[n]) * qm.z * rm[n];
        sC[(rl + 3) * SCP + cc] = (acc[m][n][3] + bj[n]) * qm.w * rm[n];
      }
    }
    LBAR();
    f32x4 v[8];
#pragma unroll
    for (int i = 0; i < 8; ++i) {
      int rl = wave * 16 + i * 2 + (lane >> 5);
      v[i] = *reinterpret_cast<const f32x4*>(&sC[rl * SCP + (lane & 31) * 4]);
    }
    LBAR();
#pragma unroll
    for (int i = 0; i < 8; ++i) {
      int rl = wave * 16 + i * 2 + (lane >> 5);
      int grow = m0 + (rl >> 5) * 128 + s * 32 + ((rl >> 4) & 1) * 16 + (rl & 15);
      __builtin_nontemporal_store(
          v[i], reinterpret_cast<f32x4*>(&C[(size_t)grow * D_OUT + n0 + (lane & 31) * 4]));
    }
  }
}

extern "C" void kernel_launch(void* const* d_in, const int* in_sizes, int n_in,
                              void* d_out, int out_size, void* d_ws, size_t ws_size,
                              hipStream_t stream) {
  const float* input     = (const float*)d_in[0];
  const float* weight    = (const float*)d_in[1];
  const float* bias      = (const float*)d_in[2];
  const float* centroids = (const float*)d_in[3];
  const int*   assign    = (const int*)d_in[4];
  float* out = (float*)d_out;

  // ws layout (bytes):
  //   A_bf16 : 0          (4 MiB)
  //   W_bf16 : 4,194,304  (16 MiB)
  //   qmask  : 20,971,520 (16 KB)
  //   cmask  : 20,987,904 (1 KB)
  //   centT4 : 21,000,192 (512 KB)
  char* ws = (char*)d_ws;
  ushort* A_bf   = (ushort*)ws;
  ushort* W_bf   = (ushort*)(ws + 4194304);
  float*  qmask  = (float*)(ws + 20971520);
  float*  cmask  = (float*)(ws + 20987904);
  float4* centT4 = (float4*)(ws + 21000192);

  prep_kernel<<<4224, 256, 0, stream>>>(weight, W_bf, centroids, centT4, cmask);
  routing_kernel<<<N_Q / 8, 256, 0, stream>>>(input, centT4, qmask, cmask, A_bf);
  gemm_masked_kernel<<<(N_Q / BM) * (D_OUT / BN), 256, 0, stream>>>(
      A_bf, W_bf, bias, assign, qmask, cmask, out);
}